// Round 1
// 309.177 us; speedup vs baseline: 1.1129x; 1.1129x over previous
//
#include <hip/hip_runtime.h>
#include <math.h>
#include <stdint.h>

typedef unsigned int u32;
typedef unsigned long long u64;

#define BLOCK 256
#define ITEMS 16
#define CHUNK (BLOCK * ITEMS)  // 4096 elements per block

// ---------------------------------------------------------------------------
// Pass 1: per-block class histograms (4 classes), int4-vectorized,
// shfl-reduced (no LDS atomic contention). Also zero-inits loss accumulator.
// ---------------------------------------------------------------------------
__global__ void __launch_bounds__(BLOCK)
hist_kernel(const int* __restrict__ labels, int N,
            u32* __restrict__ hist, double* __restrict__ acc) {
    __shared__ u32 s_cnt[4][4];  // [wave][class]
    int tid = threadIdx.x;
    int lane = tid & 63;
    int wave = tid >> 6;
    int base4 = blockIdx.x * (CHUNK / 4);
    const int4* l4 = (const int4*)labels;
    u32 c0 = 0, c1 = 0, c2 = 0, c3 = 0;
#pragma unroll
    for (int j = 0; j < ITEMS / 4; ++j) {
        int i4 = base4 + j * BLOCK + tid;
        if (4 * i4 + 3 < N) {
            int4 v = l4[i4];
            c0 += (v.x == 0) + (v.y == 0) + (v.z == 0) + (v.w == 0);
            c1 += (v.x == 1) + (v.y == 1) + (v.z == 1) + (v.w == 1);
            c2 += (v.x == 2) + (v.y == 2) + (v.z == 2) + (v.w == 2);
            c3 += (v.x == 3) + (v.y == 3) + (v.z == 3) + (v.w == 3);
        } else {
#pragma unroll
            for (int k = 0; k < 4; ++k) {
                int e = 4 * i4 + k;
                if (e < N) {
                    int l = labels[e];
                    c0 += (l == 0); c1 += (l == 1);
                    c2 += (l == 2); c3 += (l == 3);
                }
            }
        }
    }
#pragma unroll
    for (int off = 32; off > 0; off >>= 1) {
        c0 += (u32)__shfl_down((int)c0, off, 64);
        c1 += (u32)__shfl_down((int)c1, off, 64);
        c2 += (u32)__shfl_down((int)c2, off, 64);
        c3 += (u32)__shfl_down((int)c3, off, 64);
    }
    if (lane == 0) {
        s_cnt[wave][0] = c0; s_cnt[wave][1] = c1;
        s_cnt[wave][2] = c2; s_cnt[wave][3] = c3;
    }
    __syncthreads();
    if (tid < 4)
        hist[blockIdx.x * 4 + tid] =
            s_cnt[0][tid] + s_cnt[1][tid] + s_cnt[2][tid] + s_cnt[3][tid];
    if (blockIdx.x == 0 && tid == 0) *acc = 0.0;
}

// ---------------------------------------------------------------------------
// Pass 2 (fused): per-block redundant hist prefix (replaces scan kernel) +
// stable rank via ballots (phase A, lane-prefix cached in registers) +
// batched-prefetch scatter + fused analytic label write + loss.
// ---------------------------------------------------------------------------
__global__ void __launch_bounds__(BLOCK)
sort_kernel(const float4* __restrict__ data, const int* __restrict__ labels,
            int N, int nb, const u32* __restrict__ hist,
            float4* __restrict__ out_data, float* __restrict__ out_label,
            double* __restrict__ acc) {
    __shared__ u32 s_pre[ITEMS][4][4];  // [iter][wave][class]
    __shared__ u32 s_red[4][8];         // [wave][bef.xyzw, tot.xyzw]
    __shared__ u32 s_bc[8];             // b0..b3, cb1..cb3
    __shared__ double s_w[4];
    int tid = threadIdx.x;
    int lane = tid & 63;
    int wave = tid >> 6;
    int base = blockIdx.x * CHUNK;

    // --- Issue label loads early (16 independent dword loads in flight).
    int lab[ITEMS];
    u32 vmask = 0;
#pragma unroll
    for (int j = 0; j < ITEMS; ++j) {
        int idx = base + j * BLOCK + tid;
        bool valid = idx < N;
        lab[j] = valid ? labels[idx] : 0;
        vmask |= (valid ? 1u : 0u) << j;
    }

    // --- Per-block hist prefix + totals (strided coalesced uint4, L2-hot).
    uint4 bef = make_uint4(0, 0, 0, 0), tot = make_uint4(0, 0, 0, 0);
    const uint4* h4 = (const uint4*)hist;
    u32 myb = blockIdx.x;
    for (int b = tid; b < nb; b += BLOCK) {
        uint4 h = h4[b];
        tot.x += h.x; tot.y += h.y; tot.z += h.z; tot.w += h.w;
        if ((u32)b < myb) {
            bef.x += h.x; bef.y += h.y; bef.z += h.z; bef.w += h.w;
        }
    }

    // --- Phase A: ballots -> per-wave counts (LDS) + per-lane prefix
    //     (packed 8-bit x4 in registers; reused in phase B, no re-ballot).
    u64 ltm = (1ULL << lane) - 1ULL;
    u32 packed = 0;
    u32 preP[ITEMS / 4] = {0, 0, 0, 0};
#pragma unroll
    for (int j = 0; j < ITEMS; ++j) {
        bool valid = (vmask >> j) & 1;
        int l = lab[j];
        packed |= (u32)l << (2 * j);
        u64 m0 = __ballot(valid && l == 0);
        u64 m1 = __ballot(valid && l == 1);
        u64 m2 = __ballot(valid && l == 2);
        u64 m3 = __ballot(valid && l == 3);
        if (lane == 0) {
            s_pre[j][wave][0] = (u32)__popcll(m0);
            s_pre[j][wave][1] = (u32)__popcll(m1);
            s_pre[j][wave][2] = (u32)__popcll(m2);
            s_pre[j][wave][3] = (u32)__popcll(m3);
        }
        u64 mm = (l == 0) ? m0 : (l == 1) ? m1 : (l == 2) ? m2 : m3;
        preP[j >> 2] |= ((u32)__popcll(mm & ltm)) << (8 * (j & 3));
    }

    // --- Wave-reduce bef/tot into LDS.
#pragma unroll
    for (int off = 32; off > 0; off >>= 1) {
        bef.x += (u32)__shfl_down((int)bef.x, off, 64);
        bef.y += (u32)__shfl_down((int)bef.y, off, 64);
        bef.z += (u32)__shfl_down((int)bef.z, off, 64);
        bef.w += (u32)__shfl_down((int)bef.w, off, 64);
        tot.x += (u32)__shfl_down((int)tot.x, off, 64);
        tot.y += (u32)__shfl_down((int)tot.y, off, 64);
        tot.z += (u32)__shfl_down((int)tot.z, off, 64);
        tot.w += (u32)__shfl_down((int)tot.w, off, 64);
    }
    if (lane == 0) {
        s_red[wave][0] = bef.x; s_red[wave][1] = bef.y;
        s_red[wave][2] = bef.z; s_red[wave][3] = bef.w;
        s_red[wave][4] = tot.x; s_red[wave][5] = tot.y;
        s_red[wave][6] = tot.z; s_red[wave][7] = tot.w;
    }
    __syncthreads();

    // --- Scan: wave w owns class w; 64 entries in (j, wave) order.
    {
        int c = wave;
        int e = lane;
        u32 x = s_pre[e >> 2][e & 3][c];
        u32 orig = x;
#pragma unroll
        for (int off = 1; off < 64; off <<= 1) {
            u32 v = (u32)__shfl_up((int)x, off, 64);
            if (lane >= off) x += v;
        }
        s_pre[e >> 2][e & 3][c] = x - orig;  // exclusive prefix within block
    }
    if (tid == 0) {
        u32 B0 = s_red[0][0] + s_red[1][0] + s_red[2][0] + s_red[3][0];
        u32 B1 = s_red[0][1] + s_red[1][1] + s_red[2][1] + s_red[3][1];
        u32 B2 = s_red[0][2] + s_red[1][2] + s_red[2][2] + s_red[3][2];
        u32 B3 = s_red[0][3] + s_red[1][3] + s_red[2][3] + s_red[3][3];
        u32 T0 = s_red[0][4] + s_red[1][4] + s_red[2][4] + s_red[3][4];
        u32 T1 = s_red[0][5] + s_red[1][5] + s_red[2][5] + s_red[3][5];
        u32 T2 = s_red[0][6] + s_red[1][6] + s_red[2][6] + s_red[3][6];
        u32 cb1 = T0, cb2 = T0 + T1, cb3 = T0 + T1 + T2;
        s_bc[0] = B0;       s_bc[1] = cb1 + B1;
        s_bc[2] = cb2 + B2; s_bc[3] = cb3 + B3;
        s_bc[4] = cb1; s_bc[5] = cb2; s_bc[6] = cb3;
    }
    __syncthreads();

    u32 sb0 = s_bc[0], sb1 = s_bc[1], sb2 = s_bc[2], sb3 = s_bc[3];
    u32 cb1 = s_bc[4], cb2 = s_bc[5], cb3 = s_bc[6];

    // --- Phase B: batched prefetch (8 float4 + 8 rank-bases in flight),
    //     then adjust + scatter + loss. No ballots, no barriers.
    const float INV_M = 0.249999375f;  // 1/4.00001
    float loss = 0.f;
#pragma unroll
    for (int h = 0; h < 2; ++h) {
        float4 r[8];
        u32 rb[8];
#pragma unroll
        for (int k = 0; k < 8; ++k) {
            int j = h * 8 + k;
            int idx = base + j * BLOCK + tid;
            if ((vmask >> j) & 1) {
                r[k] = data[idx];
                rb[k] = s_pre[j][wave][(packed >> (2 * j)) & 3];
            }
        }
#pragma unroll
        for (int k = 0; k < 8; ++k) {
            int j = h * 8 + k;
            if ((vmask >> j) & 1) {
                int l = (packed >> (2 * j)) & 3;
                u32 pre = (preP[j >> 2] >> (8 * (j & 3))) & 255u;
                u32 bb = (l == 0) ? sb0 : (l == 1) ? sb1 : (l == 2) ? sb2 : sb3;
                u32 dst = bb + rb[k] + pre;
                float4 rr = r[k];
                float v = (l == 0) ? rr.x : (l == 1) ? rr.y
                                         : (l == 2) ? rr.z : rr.w;
                float adj = (v > 0.f) ? (v * INV_M - 0.5f)
                                      : (v * 4.00001f - 0.5f);
                if (l == 0) rr.x = adj;
                else if (l == 1) rr.y = adj;
                else if (l == 2) rr.z = adj;
                else rr.w = adj;
                out_data[dst] = rr;
                float mx = fmaxf(fmaxf(rr.x, rr.y), fmaxf(rr.z, rr.w));
                float se = __expf(rr.x - mx) + __expf(rr.y - mx) +
                           __expf(rr.z - mx) + __expf(rr.w - mx);
                loss += (mx + __logf(se)) - adj;  // -log p_true
            }
        }
    }

    // --- Fused analytic label write for this block's range.
    {
        int t4base = base >> 2;
#pragma unroll
        for (int k = 0; k < 4; ++k) {
            int t4 = t4base + k * BLOCK + tid;
            int j0 = t4 * 4;
            if (j0 + 3 < N) {
                u32 j0u = (u32)j0;
                float4 rl;
                rl.x = (float)((j0u >= cb1) + (j0u >= cb2) + (j0u >= cb3));
                rl.y = (float)((j0u + 1 >= cb1) + (j0u + 1 >= cb2) + (j0u + 1 >= cb3));
                rl.z = (float)((j0u + 2 >= cb1) + (j0u + 2 >= cb2) + (j0u + 2 >= cb3));
                rl.w = (float)((j0u + 3 >= cb1) + (j0u + 3 >= cb2) + (j0u + 3 >= cb3));
                ((float4*)out_label)[t4] = rl;
            } else {
                for (int q = 0; q < 4; ++q) {
                    int jj = j0 + q;
                    if (jj >= 0 && jj < N) {
                        u32 ju = (u32)jj;
                        out_label[jj] =
                            (float)((ju >= cb1) + (ju >= cb2) + (ju >= cb3));
                    }
                }
            }
        }
    }

    // --- Block-reduce loss in double, one atomic per block.
    double d = (double)loss;
#pragma unroll
    for (int off = 32; off > 0; off >>= 1) d += __shfl_down(d, off, 64);
    if (lane == 0) s_w[wave] = d;
    __syncthreads();
    if (tid == 0) atomicAdd(acc, s_w[0] + s_w[1] + s_w[2] + s_w[3]);
}

// ---------------------------------------------------------------------------
// Pass 3: loss finalize only (1 thread).
// ---------------------------------------------------------------------------
__global__ void finalize_kernel(const double* __restrict__ acc, int N,
                                float* __restrict__ out_loss) {
    *out_loss = (float)(*acc / (double)N);
}

// ---------------------------------------------------------------------------
extern "C" void kernel_launch(void* const* d_in, const int* in_sizes, int n_in,
                              void* d_out, int out_size, void* d_ws,
                              size_t ws_size, hipStream_t stream) {
    const float* data = (const float*)d_in[0];
    const int* labels = (const int*)d_in[1];
    int N = in_sizes[1];
    int nb = (N + CHUNK - 1) / CHUNK;

    u32* hist = (u32*)d_ws;
    double* acc =
        (double*)(((uintptr_t)(hist + (size_t)nb * 4) + 15) & ~(uintptr_t)15);

    float* out = (float*)d_out;
    float* out_data = out;                   // N*4
    float* out_label = out + (size_t)N * 4;  // N
    float* out_loss = out + (size_t)N * 5;   // 1

    hist_kernel<<<nb, BLOCK, 0, stream>>>(labels, N, hist, acc);
    sort_kernel<<<nb, BLOCK, 0, stream>>>((const float4*)data, labels, N, nb,
                                          hist, (float4*)out_data, out_label,
                                          acc);
    finalize_kernel<<<1, 1, 0, stream>>>(acc, N, out_loss);
}

// Round 2
// 300.704 us; speedup vs baseline: 1.1442x; 1.0282x over previous
//
#include <hip/hip_runtime.h>
#include <math.h>
#include <stdint.h>

typedef unsigned int u32;
typedef unsigned long long u64;

#define BLOCK 256
#define ITEMS 16
#define CHUNK (BLOCK * ITEMS)  // 4096 elements per block

// ---------------------------------------------------------------------------
// Pass 1: per-block class histograms (4 classes) + 2-bit packed labels in
// sort's exact access pattern (one u32 per (block, tid)). Coalesced scalar
// label loads (wave reads 256B/instr). Zero-inits loss accumulator.
// ---------------------------------------------------------------------------
__global__ void __launch_bounds__(BLOCK)
hist_kernel(const int* __restrict__ labels, int N,
            u32* __restrict__ hist, u32* __restrict__ plab,
            double* __restrict__ acc) {
    __shared__ u32 s_cnt[4][4];  // [wave][class]
    int tid = threadIdx.x;
    int lane = tid & 63;
    int wave = tid >> 6;
    int base = blockIdx.x * CHUNK;
    u32 packed = 0;
    u32 c0 = 0, c1 = 0, c2 = 0, c3 = 0;
#pragma unroll
    for (int j = 0; j < ITEMS; ++j) {
        int idx = base + j * BLOCK + tid;
        bool valid = idx < N;
        int l = valid ? labels[idx] : 0;
        packed |= (u32)l << (2 * j);
        c0 += (valid && l == 0);
        c1 += (valid && l == 1);
        c2 += (valid && l == 2);
        c3 += (valid && l == 3);
    }
    plab[blockIdx.x * BLOCK + tid] = packed;
#pragma unroll
    for (int off = 32; off > 0; off >>= 1) {
        c0 += (u32)__shfl_down((int)c0, off, 64);
        c1 += (u32)__shfl_down((int)c1, off, 64);
        c2 += (u32)__shfl_down((int)c2, off, 64);
        c3 += (u32)__shfl_down((int)c3, off, 64);
    }
    if (lane == 0) {
        s_cnt[wave][0] = c0; s_cnt[wave][1] = c1;
        s_cnt[wave][2] = c2; s_cnt[wave][3] = c3;
    }
    __syncthreads();
    if (tid < 4)
        hist[blockIdx.x * 4 + tid] =
            s_cnt[0][tid] + s_cnt[1][tid] + s_cnt[2][tid] + s_cnt[3][tid];
    if (blockIdx.x == 0 && tid == 0) *acc = 0.0;
}

// ---------------------------------------------------------------------------
// Pass 2 (fused): packed-label load (1 dword) + per-block hist prefix +
// ballot ranks (lane-prefix cached in registers) + software-pipelined
// data loads (batch issued BEFORE the rank phase so HBM/L3 latency hides
// under ballot/scan VALU work) + scatter + fused label write + loss.
// ---------------------------------------------------------------------------
__global__ void __launch_bounds__(BLOCK)
sort_kernel(const float4* __restrict__ data, const u32* __restrict__ plab,
            int N, int nb, const u32* __restrict__ hist,
            float4* __restrict__ out_data, float* __restrict__ out_label,
            double* __restrict__ acc) {
    __shared__ u32 s_pre[ITEMS][4][4];  // [iter][wave][class]
    __shared__ u32 s_red[4][8];         // [wave][bef.xyzw, tot.xyzw]
    __shared__ u32 s_bc[8];             // b0..b3, cb1..cb3
    __shared__ double s_w[4];
    int tid = threadIdx.x;
    int lane = tid & 63;
    int wave = tid >> 6;
    int base = blockIdx.x * CHUNK;

    // --- One dword: all 16 labels for this thread (issued first).
    u32 packed = plab[blockIdx.x * BLOCK + tid];
    u32 vmask;
    {
        int rem = N - base - tid;  // validity of idx = base + j*BLOCK + tid
        if (rem >= (ITEMS - 1) * BLOCK + 1) vmask = 0xFFFFu;
        else {
            vmask = 0;
#pragma unroll
            for (int j = 0; j < ITEMS; ++j)
                vmask |= (u32)(j * BLOCK < rem) << j;
        }
    }

    // --- Per-block hist prefix + totals (uint4, L2-hot).
    uint4 bef = make_uint4(0, 0, 0, 0), tot = make_uint4(0, 0, 0, 0);
    {
        const uint4* h4 = (const uint4*)hist;
        u32 myb = blockIdx.x;
        for (int b = tid; b < nb; b += BLOCK) {
            uint4 h = h4[b];
            tot.x += h.x; tot.y += h.y; tot.z += h.z; tot.w += h.w;
            if ((u32)b < myb) {
                bef.x += h.x; bef.y += h.y; bef.z += h.z; bef.w += h.w;
            }
        }
    }

    // --- Issue first data batch (8 float4) so it flies under rank phase.
    float4 r0[8];
#pragma unroll
    for (int k = 0; k < 8; ++k) {
        int idx = base + k * BLOCK + tid;
        if ((vmask >> k) & 1) r0[k] = data[idx];
    }

    // --- Phase A: ballots -> per-wave counts (LDS) + per-lane prefix
    //     (packed 8-bit x4 in registers; reused later, no re-ballot).
    u64 ltm = (1ULL << lane) - 1ULL;
    u32 preP[ITEMS / 4] = {0, 0, 0, 0};
#pragma unroll
    for (int j = 0; j < ITEMS; ++j) {
        bool valid = (vmask >> j) & 1;
        int l = (packed >> (2 * j)) & 3;
        u64 m0 = __ballot(valid && l == 0);
        u64 m1 = __ballot(valid && l == 1);
        u64 m2 = __ballot(valid && l == 2);
        u64 m3 = __ballot(valid && l == 3);
        if (lane == 0) {
            s_pre[j][wave][0] = (u32)__popcll(m0);
            s_pre[j][wave][1] = (u32)__popcll(m1);
            s_pre[j][wave][2] = (u32)__popcll(m2);
            s_pre[j][wave][3] = (u32)__popcll(m3);
        }
        u64 mm = (l == 0) ? m0 : (l == 1) ? m1 : (l == 2) ? m2 : m3;
        preP[j >> 2] |= ((u32)__popcll(mm & ltm)) << (8 * (j & 3));
    }

    // --- Wave-reduce bef/tot into LDS.
#pragma unroll
    for (int off = 32; off > 0; off >>= 1) {
        bef.x += (u32)__shfl_down((int)bef.x, off, 64);
        bef.y += (u32)__shfl_down((int)bef.y, off, 64);
        bef.z += (u32)__shfl_down((int)bef.z, off, 64);
        bef.w += (u32)__shfl_down((int)bef.w, off, 64);
        tot.x += (u32)__shfl_down((int)tot.x, off, 64);
        tot.y += (u32)__shfl_down((int)tot.y, off, 64);
        tot.z += (u32)__shfl_down((int)tot.z, off, 64);
        tot.w += (u32)__shfl_down((int)tot.w, off, 64);
    }
    if (lane == 0) {
        s_red[wave][0] = bef.x; s_red[wave][1] = bef.y;
        s_red[wave][2] = bef.z; s_red[wave][3] = bef.w;
        s_red[wave][4] = tot.x; s_red[wave][5] = tot.y;
        s_red[wave][6] = tot.z; s_red[wave][7] = tot.w;
    }
    __syncthreads();

    // --- Scan: wave w owns class w; 64 entries in (j, wave) order.
    {
        int c = wave;
        int e = lane;
        u32 x = s_pre[e >> 2][e & 3][c];
        u32 orig = x;
#pragma unroll
        for (int off = 1; off < 64; off <<= 1) {
            u32 v = (u32)__shfl_up((int)x, off, 64);
            if (lane >= off) x += v;
        }
        s_pre[e >> 2][e & 3][c] = x - orig;  // exclusive prefix within block
    }
    if (tid == 0) {
        u32 B0 = s_red[0][0] + s_red[1][0] + s_red[2][0] + s_red[3][0];
        u32 B1 = s_red[0][1] + s_red[1][1] + s_red[2][1] + s_red[3][1];
        u32 B2 = s_red[0][2] + s_red[1][2] + s_red[2][2] + s_red[3][2];
        u32 B3 = s_red[0][3] + s_red[1][3] + s_red[2][3] + s_red[3][3];
        u32 T0 = s_red[0][4] + s_red[1][4] + s_red[2][4] + s_red[3][4];
        u32 T1 = s_red[0][5] + s_red[1][5] + s_red[2][5] + s_red[3][5];
        u32 T2 = s_red[0][6] + s_red[1][6] + s_red[2][6] + s_red[3][6];
        u32 cb1 = T0, cb2 = T0 + T1, cb3 = T0 + T1 + T2;
        s_bc[0] = B0;       s_bc[1] = cb1 + B1;
        s_bc[2] = cb2 + B2; s_bc[3] = cb3 + B3;
        s_bc[4] = cb1; s_bc[5] = cb2; s_bc[6] = cb3;
    }
    __syncthreads();

    u32 sb0 = s_bc[0], sb1 = s_bc[1], sb2 = s_bc[2], sb3 = s_bc[3];
    u32 cb1 = s_bc[4], cb2 = s_bc[5], cb3 = s_bc[6];

    // --- Issue second data batch before touching r0 (keeps pipe full).
    float4 r1[8];
#pragma unroll
    for (int k = 0; k < 8; ++k) {
        int j = 8 + k;
        int idx = base + j * BLOCK + tid;
        if ((vmask >> j) & 1) r1[k] = data[idx];
    }

    // --- Process both batches: adjust + scatter + loss.
    const float INV_M = 0.249999375f;  // 1/4.00001
    float loss = 0.f;
#pragma unroll
    for (int k = 0; k < 8; ++k) {
        int j = k;
        if ((vmask >> j) & 1) {
            int l = (packed >> (2 * j)) & 3;
            u32 pre = (preP[j >> 2] >> (8 * (j & 3))) & 255u;
            u32 bb = (l == 0) ? sb0 : (l == 1) ? sb1 : (l == 2) ? sb2 : sb3;
            u32 dst = bb + s_pre[j][wave][l] + pre;
            float4 rr = r0[k];
            float v = (l == 0) ? rr.x : (l == 1) ? rr.y
                                     : (l == 2) ? rr.z : rr.w;
            float adj = (v > 0.f) ? (v * INV_M - 0.5f) : (v * 4.00001f - 0.5f);
            if (l == 0) rr.x = adj;
            else if (l == 1) rr.y = adj;
            else if (l == 2) rr.z = adj;
            else rr.w = adj;
            out_data[dst] = rr;
            float mx = fmaxf(fmaxf(rr.x, rr.y), fmaxf(rr.z, rr.w));
            float se = __expf(rr.x - mx) + __expf(rr.y - mx) +
                       __expf(rr.z - mx) + __expf(rr.w - mx);
            loss += (mx + __logf(se)) - adj;  // -log p_true
        }
    }
#pragma unroll
    for (int k = 0; k < 8; ++k) {
        int j = 8 + k;
        if ((vmask >> j) & 1) {
            int l = (packed >> (2 * j)) & 3;
            u32 pre = (preP[j >> 2] >> (8 * (j & 3))) & 255u;
            u32 bb = (l == 0) ? sb0 : (l == 1) ? sb1 : (l == 2) ? sb2 : sb3;
            u32 dst = bb + s_pre[j][wave][l] + pre;
            float4 rr = r1[k];
            float v = (l == 0) ? rr.x : (l == 1) ? rr.y
                                     : (l == 2) ? rr.z : rr.w;
            float adj = (v > 0.f) ? (v * INV_M - 0.5f) : (v * 4.00001f - 0.5f);
            if (l == 0) rr.x = adj;
            else if (l == 1) rr.y = adj;
            else if (l == 2) rr.z = adj;
            else rr.w = adj;
            out_data[dst] = rr;
            float mx = fmaxf(fmaxf(rr.x, rr.y), fmaxf(rr.z, rr.w));
            float se = __expf(rr.x - mx) + __expf(rr.y - mx) +
                       __expf(rr.z - mx) + __expf(rr.w - mx);
            loss += (mx + __logf(se)) - adj;  // -log p_true
        }
    }

    // --- Fused analytic label write for this block's range.
    {
        int t4base = base >> 2;
#pragma unroll
        for (int k = 0; k < 4; ++k) {
            int t4 = t4base + k * BLOCK + tid;
            int j0 = t4 * 4;
            if (j0 + 3 < N) {
                u32 j0u = (u32)j0;
                float4 rl;
                rl.x = (float)((j0u >= cb1) + (j0u >= cb2) + (j0u >= cb3));
                rl.y = (float)((j0u + 1 >= cb1) + (j0u + 1 >= cb2) + (j0u + 1 >= cb3));
                rl.z = (float)((j0u + 2 >= cb1) + (j0u + 2 >= cb2) + (j0u + 2 >= cb3));
                rl.w = (float)((j0u + 3 >= cb1) + (j0u + 3 >= cb2) + (j0u + 3 >= cb3));
                ((float4*)out_label)[t4] = rl;
            } else {
                for (int q = 0; q < 4; ++q) {
                    int jj = j0 + q;
                    if (jj >= 0 && jj < N) {
                        u32 ju = (u32)jj;
                        out_label[jj] =
                            (float)((ju >= cb1) + (ju >= cb2) + (ju >= cb3));
                    }
                }
            }
        }
    }

    // --- Block-reduce loss in double, one atomic per block.
    double d = (double)loss;
#pragma unroll
    for (int off = 32; off > 0; off >>= 1) d += __shfl_down(d, off, 64);
    if (lane == 0) s_w[wave] = d;
    __syncthreads();
    if (tid == 0) atomicAdd(acc, s_w[0] + s_w[1] + s_w[2] + s_w[3]);
}

// ---------------------------------------------------------------------------
// Pass 3: loss finalize only (1 thread).
// ---------------------------------------------------------------------------
__global__ void finalize_kernel(const double* __restrict__ acc, int N,
                                float* __restrict__ out_loss) {
    *out_loss = (float)(*acc / (double)N);
}

// ---------------------------------------------------------------------------
extern "C" void kernel_launch(void* const* d_in, const int* in_sizes, int n_in,
                              void* d_out, int out_size, void* d_ws,
                              size_t ws_size, hipStream_t stream) {
    const float* data = (const float*)d_in[0];
    const int* labels = (const int*)d_in[1];
    int N = in_sizes[1];
    int nb = (N + CHUNK - 1) / CHUNK;

    u32* hist = (u32*)d_ws;                     // nb*4 u32
    u32* plab = hist + (size_t)nb * 4;          // nb*BLOCK u32 (packed labels)
    double* acc =
        (double*)(((uintptr_t)(plab + (size_t)nb * BLOCK) + 15) &
                  ~(uintptr_t)15);

    float* out = (float*)d_out;
    float* out_data = out;                   // N*4
    float* out_label = out + (size_t)N * 4;  // N
    float* out_loss = out + (size_t)N * 5;   // 1

    hist_kernel<<<nb, BLOCK, 0, stream>>>(labels, N, hist, plab, acc);
    sort_kernel<<<nb, BLOCK, 0, stream>>>((const float4*)data, plab, N, nb,
                                          hist, (float4*)out_data, out_label,
                                          acc);
    finalize_kernel<<<1, 1, 0, stream>>>(acc, N, out_loss);
}